// Round 9
// baseline (1553.721 us; speedup 1.0000x reference)
//
#include <hip/hip_runtime.h>
#include <hip/hip_bf16.h>

typedef unsigned short u16;
typedef unsigned char u8;

// Problem constants: B_=2, T=4096, DIM=1024, HEADS=16, DH=64, NH(rounds)=8,
// NB(buckets)=64, BUCKET=64, merged batch-heads M=32, chunks/merged-head=512.
//
// ROUND 19 (session r8): r7 bisect: 128^2 tile w/ single acc[8][8] (out_gemm)
// is REPLAY-SAFE; r6's fold-constrained qkv (acc+accT = 128 live floats,
// spill boundary) was the tripwire culprit. This round: 128^2 qkv WITHOUT
// accT — OpenBLAS's own memory-materialized panel accumulation: C = p0;
// C += p1; C += p2 via flush-to-dst at fold points (plain store for panel 0,
// load+add+store after). IEEE add is commutative bitwise -> per-element value
// still ((p0+p1)+p2), bit-identical. ~256MB extra HBM (~40us) buys 2x fewer
// LDS-read instrs and 4x fewer blocks.
// BIT-EXACTNESS INVARIANTS (calibrated to host OpenBLAS, r1 PASS):
//  - qk GEMM: per-element fp32 FMA chain ascending k, panel folds {384,704},
//    panel sums combined by plain adds in panel order. DO NOT TOUCH.
//  - hash: ascending-f FMA chain, argmax first-occurrence strict >/<.

__device__ __forceinline__ bool qk_fold_point(int k0) {
    return k0 == 384 || k0 == 704;
}

// ---- scratch in static device globals ----
__device__ static float g_qk32[32u * 4096u * 64u];   // 32 MB [m][t][d]
__device__ static float g_v32 [32u * 4096u * 64u];   // 32 MB
__device__ static float g_ctx [2u * 4096u * 1024u];  // 32 MB [b][t][head*64+d]
__device__ static float g_bo  [32u * 8u * 4096u * 64u]; // 256 MB [m][h][t][d]
__device__ static float g_logits[32u * 8u * 4096u];  //  4 MB [m][h][t]
__device__ static u16   g_st  [32u * 8u * 4096u];    //  2 MB sorted token idx
__device__ static u8    g_bkt [32u * 8u * 4096u];    //  1 MB bucket ids

// ---------------------------------------------------------------------------
// Kernel 1a: qkv GEMM. 128x128 C tile, 8x8 per thread, K-step 32, RMW
// fold-flush. grid (64, 16): bn<8 -> qk head pair bn, bn>=8 -> v pair bn-8.
// LDS 41.5KB. Single acc[8][8] (replay-proven footprint).
// ---------------------------------------------------------------------------
__global__ __launch_bounds__(256) void qkv_gemm(
    const float* __restrict__ x, const float* __restrict__ w_qk,
    const float* __restrict__ w_v)
{
    __shared__ __align__(16) float As[32 * 132];  // [kk][row]
    __shared__ __align__(16) float Ws[32 * 192];  // [kk][(c>>3)*12 + (c&7)]
    const int tid = threadIdx.x;
    const int bm = blockIdx.x;          // 64 row tiles of 128
    const int bn = blockIdx.y;          // 0..7 qk, 8..15 v
    const bool is_v = bn >= 8;
    const float* __restrict__ w = is_v ? w_v : w_qk;
    const int hp = is_v ? bn - 8 : bn;  // head pair index
    const int ncol0 = hp * 128;
    const int row0 = bm * 128;
    const int tx = tid & 15, ty = tid >> 4;
    const int lr = tid >> 1;            // loader row/col 0..127
    const int lk = (tid & 1) * 16;      // loader k offset {0,16}
    float acc[8][8] = {};               // within-panel FMA chain only

    const int b_ = row0 >> 12;             // batch (tile never straddles)
    const int head = hp * 2 + (tx >> 3);   // thread's 8 cols stay in one head
    const int m = b_ * 16 + head;
    const int d0 = (tx * 8) & 63;
    float* __restrict__ dst = is_v ? g_v32 : g_qk32;
    int first_panel = 1;

    for (int k0 = 0; k0 < 1024; k0 += 32) {
        if (qk_fold_point(k0)) {
            // OpenBLAS panel boundary: C (+)= panel, then new chain
#pragma unroll
            for (int i = 0; i < 8; i++) {
                const int t = (row0 & 4095) + ty * 8 + i;
                float* __restrict__ cp =
                    &dst[(((size_t)m * 4096 + t) << 6) + d0];
                float4 s0, s1;
                s0.x = acc[i][0]; s0.y = acc[i][1];
                s0.z = acc[i][2]; s0.w = acc[i][3];
                s1.x = acc[i][4]; s1.y = acc[i][5];
                s1.z = acc[i][6]; s1.w = acc[i][7];
                if (!first_panel) {
                    const float4 c0 = *(const float4*)&cp[0];
                    const float4 c1 = *(const float4*)&cp[4];
                    s0.x += c0.x; s0.y += c0.y; s0.z += c0.z; s0.w += c0.w;
                    s1.x += c1.x; s1.y += c1.y; s1.z += c1.z; s1.w += c1.w;
                }
                *(float4*)&cp[0] = s0;
                *(float4*)&cp[4] = s1;
#pragma unroll
                for (int j = 0; j < 8; j++) acc[i][j] = 0.f;
            }
            first_panel = 0;
        }
        float av[16], wv[16];
#pragma unroll
        for (int q4 = 0; q4 < 4; q4++) {
            *(float4*)&av[q4 * 4] =
                *(const float4*)(x + (size_t)(row0 + lr) * 1024 + k0 + lk + q4 * 4);
            *(float4*)&wv[q4 * 4] =
                *(const float4*)(w + (size_t)(ncol0 + lr) * 1024 + k0 + lk + q4 * 4);
        }
        __syncthreads();
#pragma unroll
        for (int q = 0; q < 16; q++) {
            As[(lk + q) * 132 + lr] = av[q];
            Ws[(lk + q) * 192 + (lr >> 3) * 12 + (lr & 7)] = wv[q];
        }
        __syncthreads();
        // per-element: acc = fma(a_k, b_k, acc), k strictly ascending in-panel
#pragma unroll 4
        for (int kk = 0; kk < 32; kk++) {
            const float4 a0 = *(const float4*)&As[kk * 132 + ty * 8];
            const float4 a1 = *(const float4*)&As[kk * 132 + ty * 8 + 4];
            const float4 b0 = *(const float4*)&Ws[kk * 192 + tx * 12];
            const float4 b1 = *(const float4*)&Ws[kk * 192 + tx * 12 + 4];
            const float aa[8] = {a0.x, a0.y, a0.z, a0.w, a1.x, a1.y, a1.z, a1.w};
            const float bb[8] = {b0.x, b0.y, b0.z, b0.w, b1.x, b1.y, b1.z, b1.w};
#pragma unroll
            for (int i = 0; i < 8; i++)
#pragma unroll
                for (int j = 0; j < 8; j++)
                    acc[i][j] = fmaf(aa[i], bb[j], acc[i][j]);
        }
    }
    // final panel flush: C += p_last
#pragma unroll
    for (int i = 0; i < 8; i++) {
        const int t = (row0 & 4095) + ty * 8 + i;
        float* __restrict__ cp = &dst[(((size_t)m * 4096 + t) << 6) + d0];
        const float4 c0 = *(const float4*)&cp[0];
        const float4 c1 = *(const float4*)&cp[4];
        float4 s0, s1;
        s0.x = acc[i][0] + c0.x; s0.y = acc[i][1] + c0.y;
        s0.z = acc[i][2] + c0.z; s0.w = acc[i][3] + c0.w;
        s1.x = acc[i][4] + c1.x; s1.y = acc[i][5] + c1.y;
        s1.z = acc[i][6] + c1.z; s1.w = acc[i][7] + c1.w;
        *(float4*)&cp[0] = s0;
        *(float4*)&cp[4] = s1;
    }
}

// ---------------------------------------------------------------------------
// Kernel 1b: LSH hash. One thread per (m,t) row: q in 64 VGPRs, rotations
// staged in LDS [f][h][i] (i contiguous -> b128 reads, lane-uniform
// broadcast). Per (hh, i): exact ascending-f fp32 FMA chain; 4 independent
// chains per rot read. argmax([rot,-rot]) first-occurrence via strict >/<.
// grid 512, block 256. LDS 64KB -> 2 blocks/CU.
// ---------------------------------------------------------------------------
__global__ __launch_bounds__(256) void hash_kernel(
    const float* __restrict__ rot_in)
{
    __shared__ __align__(16) float rotS[16384];  // [f][h][i]
    const int tid = threadIdx.x;
    for (int idx = tid; idx < 16384; idx += 256)
        rotS[idx] = rot_in[idx];
    __syncthreads();
    const int row = blockIdx.x * 256 + tid;      // m*4096 + t
    const int m = row >> 12, t = row & 4095;
    float q[64];
    const float* __restrict__ qp = g_qk32 + ((size_t)row << 6);
#pragma unroll
    for (int f4 = 0; f4 < 16; f4++)
        *(float4*)&q[f4 * 4] = *(const float4*)&qp[f4 * 4];
#pragma unroll 1
    for (int hh = 0; hh < 8; hh++) {
        float bp = -3.4e38f; int ip = 0;
        float mn = 3.4e38f;  int im = 0;
#pragma unroll 1
        for (int ib = 0; ib < 8; ib++) {
            float s0 = 0.f, s1 = 0.f, s2 = 0.f, s3 = 0.f;
#pragma unroll
            for (int f = 0; f < 64; f++) {
                const float4 r4 =
                    *(const float4*)&rotS[f * 256 + hh * 32 + ib * 4];
                const float qf = q[f];
                s0 = fmaf(qf, r4.x, s0);
                s1 = fmaf(qf, r4.y, s1);
                s2 = fmaf(qf, r4.z, s2);
                s3 = fmaf(qf, r4.w, s3);
            }
            const int i0 = ib * 4;
            if (s0 > bp) { bp = s0; ip = i0; }
            if (s0 < mn) { mn = s0; im = i0; }
            if (s1 > bp) { bp = s1; ip = i0 + 1; }
            if (s1 < mn) { mn = s1; im = i0 + 1; }
            if (s2 > bp) { bp = s2; ip = i0 + 2; }
            if (s2 < mn) { mn = s2; im = i0 + 2; }
            if (s3 > bp) { bp = s3; ip = i0 + 3; }
            if (s3 < mn) { mn = s3; im = i0 + 3; }
        }
        const int bi = (-mn > bp) ? (32 + im) : ip;
        g_bkt[((size_t)m * 8 + hh) * 4096 + t] = (u8)bi;
    }
}

// ---------------------------------------------------------------------------
// Kernel 2: per-(m,h) stable counting sort of 4096 tokens into 64 buckets.
// ---------------------------------------------------------------------------
__global__ __launch_bounds__(256) void sort_kernel()
{
    __shared__ u16 hist[256 * 64];   // [chunk][bucket]
    __shared__ u8 bkt[4096];
    __shared__ int rowsum[64];
    __shared__ int rowbase[64];
    const int tid = threadIdx.x;
    const int mh = blockIdx.x;
    const u8* __restrict__ src = g_bkt + (size_t)mh * 4096;
    for (int i = tid; i < 4096; i += 256) bkt[i] = src[i];
    for (int i = tid; i < 16384; i += 256) hist[i] = 0;
    __syncthreads();
#pragma unroll
    for (int k = 0; k < 16; k++) {
        const int t = tid * 16 + k;
        hist[tid * 64 + (bkt[t] & 63)]++;  // own row -> race-free, stable
    }
    __syncthreads();
    if (tid < 64) {
        int s = 0;
        for (int c = 0; c < 256; c++) s += hist[c * 64 + tid];
        rowsum[tid] = s;
    }
    __syncthreads();
    if (tid == 0) {
        int acc = 0;
        for (int b = 0; b < 64; b++) { rowbase[b] = acc; acc += rowsum[b]; }
    }
    __syncthreads();
    if (tid < 64) {
        int run = rowbase[tid];
        for (int c = 0; c < 256; c++) {
            const int tmp = hist[c * 64 + tid];
            hist[c * 64 + tid] = (u16)run;
            run += tmp;
        }
    }
    __syncthreads();
    u16* __restrict__ dst = g_st + (size_t)mh * 4096;
#pragma unroll
    for (int k = 0; k < 16; k++) {
        const int t = tid * 16 + k;
        const int b = bkt[t] & 63;
        const int pos = hist[tid * 64 + b]++;
        dst[pos & 4095] = (u16)t;
    }
}

// ---------------------------------------------------------------------------
// Kernel 3: fused per-chunk attention, register-tiled 4 rows x 8 keys.
// Thread map: rg = tid>>4 (rows rg*4+i), kg = tid&15 (keys jj*16+kg in dots,
// dims kg*4 in PV). p staged transposed into the dead ks buffer for PV.
// grid 16384 = 32*512, block 256. LDS 68.6KB.
// ---------------------------------------------------------------------------
__global__ __launch_bounds__(256) void attn_chunk()
{
    __shared__ __align__(16) float ks[128 * 68];   // K tile; reused as p^T
    __shared__ __align__(16) float vs[128 * 64];
    __shared__ float rnorm[128];
    __shared__ int tk[128];
    const int tid = threadIdx.x;
    const int bid = blockIdx.x;
    const int m = bid >> 9, c = bid & 511;
    const int h = c >> 6, cc = c & 63;
    const int cp = (c + 511) & 511;            // look-one-back, wraps all 512
    const int hp = cp >> 6, ccp = cp & 63;
    const u16* __restrict__ stm = g_st + (size_t)m * 8 * 4096;
    if (tid < 128) {
        const int hh = (tid < 64) ? h : hp;
        const int cq = (tid < 64) ? cc : ccp;
        tk[tid] = (int)stm[hh * 4096 + cq * 64 + (tid & 63)] & 4095;
    }
    __syncthreads();
    const float* __restrict__ qkm = g_qk32 + ((size_t)m << 18);
    const float* __restrict__ vm = g_v32 + ((size_t)m << 18);
    for (int idx = tid; idx < 128 * 16; idx += 256) {
        const int j = idx >> 4, f4 = idx & 15;
        const size_t so = ((size_t)tk[j] << 6) + f4 * 4;
        *(float4*)&ks[j * 68 + f4 * 4] = *(const float4*)&qkm[so];
        *(float4*)&vs[j * 64 + f4 * 4] = *(const float4*)&vm[so];
    }
    __syncthreads();
    if (tid < 128) {
        float ss = 0.f;
#pragma unroll
        for (int f4 = 0; f4 < 16; f4++) {
            const float4 v = *(const float4*)&ks[tid * 68 + f4 * 4];
            ss += v.x * v.x + v.y * v.y + v.z * v.z + v.w * v.w;
        }
        rnorm[tid] = 1.0f / fmaxf(sqrtf(ss), 1e-12f);
    }
    __syncthreads();
    const int rg = tid >> 4;          // rows rg*4 + i
    const int kg = tid & 15;          // keys jj*16+kg / dims kg*4
    int myq[4];
#pragma unroll
    for (int i = 0; i < 4; i++) myq[i] = tk[rg * 4 + i];
    int tkj[8]; float rn[8];
#pragma unroll
    for (int jj = 0; jj < 8; jj++) {
        tkj[jj] = tk[jj * 16 + kg];
        rn[jj] = rnorm[jj * 16 + kg] * 0.125f;
    }
    float acc[4][8];
#pragma unroll
    for (int i = 0; i < 4; i++)
#pragma unroll
        for (int jj = 0; jj < 8; jj++) acc[i][jj] = 0.f;
    // --- dots: 4 rows x 8 keys per thread; 12 b128 reads per f4 step ---
#pragma unroll 2
    for (int f4 = 0; f4 < 16; f4++) {
        float4 q[4];
#pragma unroll
        for (int i = 0; i < 4; i++)
            q[i] = *(const float4*)&ks[(rg * 4 + i) * 68 + f4 * 4];
#pragma unroll
        for (int jj = 0; jj < 8; jj++) {
            const float4 kv = *(const float4*)&ks[(jj * 16 + kg) * 68 + f4 * 4];
#pragma unroll
            for (int i = 0; i < 4; i++)
                acc[i][jj] += q[i].x * kv.x + q[i].y * kv.y
                            + q[i].z * kv.z + q[i].w * kv.w;
        }
    }
    // --- mask/clamp + row softmax (16-lane reduce over kg) ---
    float inv_s[4], lse_[4];
#pragma unroll
    for (int i = 0; i < 4; i++) {
        float mx = -3.4e38f;
#pragma unroll
        for (int jj = 0; jj < 8; jj++) {
            float a = acc[i][jj];
            a = (myq[i] == tkj[jj]) ? -50000.f
                : fminf(fmaxf(a * rn[jj], -30.f), 30.f);
            acc[i][jj] = a;
            mx = fmaxf(mx, a);
        }
        mx = fmaxf(mx, __shfl_xor(mx, 1));
        mx = fmaxf(mx, __shfl_xor(mx, 2));
        mx = fmaxf(mx, __shfl_xor(mx, 4));
        mx = fmaxf(mx, __shfl_xor(mx, 8));
        float s = 0.f;
#pragma unroll
        for (int jj = 0; jj < 8; jj++) {
            const float e = __expf(acc[i][jj] - mx);
            acc[i][jj] = e;
            s += e;
        }
        s += __shfl_xor(s, 1);
        s += __shfl_xor(s, 2);
        s += __shfl_xor(s, 4);
        s += __shfl_xor(s, 8);
        inv_s[i] = 1.0f / s;
        lse_[i] = mx + __logf(s);
    }
    __syncthreads();   // all ks reads done -> safe to overwrite with p^T
    // --- stage normalized p transposed: pT[key j][row] in ks buffer ---
#pragma unroll
    for (int jj = 0; jj < 8; jj++) {
        float4 pv;
        pv.x = acc[0][jj] * inv_s[0];
        pv.y = acc[1][jj] * inv_s[1];
        pv.z = acc[2][jj] * inv_s[2];
        pv.w = acc[3][jj] * inv_s[3];
        *(float4*)&ks[(jj * 16 + kg) * 68 + rg * 4] = pv;
    }
    if (kg == 0) {
#pragma unroll
        for (int i = 0; i < 4; i++)
            g_logits[((size_t)m * 8 + h) * 4096 + myq[i]] = lse_[i];
    }
    __syncthreads();
    // --- PV: rows rg*4+i, dims kg*4; 2 b128 reads / 16 FMA per key ---
    float4 o[4];
#pragma unroll
    for (int i = 0; i < 4; i++) o[i] = float4{0.f, 0.f, 0.f, 0.f};
#pragma unroll 4
    for (int j = 0; j < 128; j++) {
        const float4 pv = *(const float4*)&ks[j * 68 + rg * 4];
        const float4 vv = *(const float4*)&vs[j * 64 + kg * 4];
        o[0].x += pv.x * vv.x; o[0].y += pv.x * vv.y;
        o[0].z += pv.x * vv.z; o[0].w += pv.x * vv.w;
        o[1].x += pv.y * vv.x; o[1].y += pv.y * vv.y;
        o[1].z += pv.y * vv.z; o[1].w += pv.y * vv.w;
        o[2].x += pv.z * vv.x; o[2].y += pv.z * vv.y;
        o[2].z += pv.z * vv.z; o[2].w += pv.z * vv.w;
        o[3].x += pv.w * vv.x; o[3].y += pv.w * vv.y;
        o[3].z += pv.w * vv.z; o[3].w += pv.w * vv.w;
    }
    float* __restrict__ bo = g_bo + ((((size_t)m * 8 + h) * 4096) << 6);
#pragma unroll
    for (int i = 0; i < 4; i++)
        *(float4*)&bo[((size_t)myq[i] << 6) + kg * 4] = o[i];
}

// ---------------------------------------------------------------------------
// Kernel 4: round combination: softmax over 8 logits per (m,t), weighted sum
// of per-round outputs -> g_ctx. grid 2048, block 256 (thread = (m,t,16dims)).
// ---------------------------------------------------------------------------
__global__ __launch_bounds__(256) void combine()
{
    const int idx = blockIdx.x * 256 + threadIdx.x;
    const int g = idx & 3;                 // 16-dim group
    const int t = (idx >> 2) & 4095;
    const int m = idx >> 14;
    const float* __restrict__ lg = g_logits + (size_t)m * 8 * 4096 + t;
    float l[8], mx = -3.4e38f;
#pragma unroll
    for (int h = 0; h < 8; h++) {
        l[h] = lg[(size_t)h * 4096];
        mx = fmaxf(mx, l[h]);
    }
    float s = 0.f;
#pragma unroll
    for (int h = 0; h < 8; h++) { l[h] = __expf(l[h] - mx); s += l[h]; }
    const float inv = 1.0f / s;
    const float* __restrict__ bo = g_bo
        + (((size_t)m * 8) * 4096 + t) * 64 + g * 16;
    float4 o0 = {0, 0, 0, 0}, o1 = {0, 0, 0, 0}, o2 = {0, 0, 0, 0}, o3 = {0, 0, 0, 0};
#pragma unroll
    for (int h = 0; h < 8; h++) {
        const float w = l[h] * inv;
        const size_t ho = (size_t)h * 4096 * 64;
        const float4 v0 = *(const float4*)&bo[ho + 0];
        const float4 v1 = *(const float4*)&bo[ho + 4];
        const float4 v2 = *(const float4*)&bo[ho + 8];
        const float4 v3 = *(const float4*)&bo[ho + 12];
        o0.x += w * v0.x; o0.y += w * v0.y; o0.z += w * v0.z; o0.w += w * v0.w;
        o1.x += w * v1.x; o1.y += w * v1.y; o1.z += w * v1.z; o1.w += w * v1.w;
        o2.x += w * v2.x; o2.y += w * v2.y; o2.z += w * v2.z; o2.w += w * v2.w;
        o3.x += w * v3.x; o3.y += w * v3.y; o3.z += w * v3.z; o3.w += w * v3.w;
    }
    float* __restrict__ cd = g_ctx
        + ((size_t)(m >> 4) * 4096 + t) * 1024 + (m & 15) * 64 + g * 16;
    *(float4*)&cd[0]  = o0;
    *(float4*)&cd[4]  = o1;
    *(float4*)&cd[8]  = o2;
    *(float4*)&cd[12] = o3;
}

// ---------------------------------------------------------------------------
// Kernel 5: out = ctx @ w_out^T + b_out. 128x128 tile, 8x8 per thread.
// grid (64, 8). Continuous path (no chain constraint, single acc[8][8]).
// ---------------------------------------------------------------------------
__global__ __launch_bounds__(256) void out_gemm(
    const float* __restrict__ w_out, const float* __restrict__ b_out,
    float* __restrict__ out)
{
    __shared__ __align__(16) float As[32 * 132];
    __shared__ __align__(16) float Ws[32 * 192];
    const int tid = threadIdx.x;
    const int bm = blockIdx.x, bn = blockIdx.y;
    const int row0 = bm * 128, col0 = bn * 128;
    const int tx = tid & 15, ty = tid >> 4;
    const int lr = tid >> 1;
    const int lk = (tid & 1) * 16;
    float acc[8][8] = {};

    for (int k0 = 0; k0 < 1024; k0 += 32) {
        float av[16], wv[16];
#pragma unroll
        for (int q4 = 0; q4 < 4; q4++) {
            *(float4*)&av[q4 * 4] =
                *(const float4*)(g_ctx + (size_t)(row0 + lr) * 1024 + k0 + lk + q4 * 4);
            *(float4*)&wv[q4 * 4] =
                *(const float4*)(w_out + (size_t)(col0 + lr) * 1024 + k0 + lk + q4 * 4);
        }
        __syncthreads();
#pragma unroll
        for (int q = 0; q < 16; q++) {
            As[(lk + q) * 132 + lr] = av[q];
            Ws[(lk + q) * 192 + (lr >> 3) * 12 + (lr & 7)] = wv[q];
        }
        __syncthreads();
#pragma unroll 4
        for (int kk = 0; kk < 32; kk++) {
            const float4 a0 = *(const float4*)&As[kk * 132 + ty * 8];
            const float4 a1 = *(const float4*)&As[kk * 132 + ty * 8 + 4];
            const float4 b0 = *(const float4*)&Ws[kk * 192 + tx * 12];
            const float4 b1 = *(const float4*)&Ws[kk * 192 + tx * 12 + 4];
            const float aa[8] = {a0.x, a0.y, a0.z, a0.w, a1.x, a1.y, a1.z, a1.w};
            const float bb[8] = {b0.x, b0.y, b0.z, b0.w, b1.x, b1.y, b1.z, b1.w};
#pragma unroll
            for (int i = 0; i < 8; i++)
#pragma unroll
                for (int j = 0; j < 8; j++)
                    acc[i][j] = fmaf(aa[i], bb[j], acc[i][j]);
        }
    }
#pragma unroll
    for (int i = 0; i < 8; i++) {
        const int row = row0 + ty * 8 + i;
        float4 s0, s1;
        s0.x = acc[i][0] + b_out[col0 + tx * 8 + 0];
        s0.y = acc[i][1] + b_out[col0 + tx * 8 + 1];
        s0.z = acc[i][2] + b_out[col0 + tx * 8 + 2];
        s0.w = acc[i][3] + b_out[col0 + tx * 8 + 3];
        s1.x = acc[i][4] + b_out[col0 + tx * 8 + 4];
        s1.y = acc[i][5] + b_out[col0 + tx * 8 + 5];
        s1.z = acc[i][6] + b_out[col0 + tx * 8 + 6];
        s1.w = acc[i][7] + b_out[col0 + tx * 8 + 7];
        *(float4*)&out[(size_t)row * 1024 + col0 + tx * 8] = s0;
        *(float4*)&out[(size_t)row * 1024 + col0 + tx * 8 + 4] = s1;
    }
}

// ---------------------------------------------------------------------------
extern "C" void kernel_launch(void* const* d_in, const int* in_sizes, int n_in,
                              void* d_out, int out_size, void* d_ws, size_t ws_size,
                              hipStream_t stream)
{
    (void)in_sizes; (void)n_in; (void)out_size; (void)d_ws; (void)ws_size;
    const float* x     = (const float*)d_in[0];
    const float* w_qk  = (const float*)d_in[1];
    const float* w_v   = (const float*)d_in[2];
    const float* w_out = (const float*)d_in[3];
    const float* b_out = (const float*)d_in[4];
    const float* rot   = (const float*)d_in[5];

    qkv_gemm<<<dim3(64, 16), 256, 0, stream>>>(x, w_qk, w_v);
    hash_kernel<<<512, 256, 0, stream>>>(rot);
    sort_kernel<<<256, 256, 0, stream>>>();
    attn_chunk<<<16384, 256, 0, stream>>>();
    combine<<<2048, 256, 0, stream>>>();
    out_gemm<<<dim3(64, 8), 256, 0, stream>>>(w_out, b_out, (float*)d_out);
}

// Round 11
// 1296.499 us; speedup vs baseline: 1.1984x; 1.1984x over previous
//
#include <hip/hip_runtime.h>
#include <hip/hip_bf16.h>

typedef unsigned short u16;
typedef unsigned char u8;

// Problem constants: B_=2, T=4096, DIM=1024, HEADS=16, DH=64, NH(rounds)=8,
// NB(buckets)=64, BUCKET=64, merged batch-heads M=32, chunks/merged-head=512.
//
// ROUND 21 (session r10): resubmit of r9 (infra failure, no data).
// r9 design: attn_chunk MFMA conversion. It was LDS-instruction bound
// (700us, ~470 LDS instrs/wave x 12cyc ~ 570us, vs 219us fp32 FMA floor).
// New: bf16 hi/lo split (x = hi + lo, 3 MFMAs hi*hi+hi*lo+lo*hi, rel err
// ~2^-18) for dots AND PV via v_mfma_f32_16x16x32_bf16.
// Fragment layouts (m89-verified C/D; standard CDNA A/B):
//   A[row=lane&15][k=(lane>>4)*8+e], B[col=lane&15][k=(lane>>4)*8+e],
//   D[row=(lane>>4)*4+reg][col=lane&15].
// K staged [key][f] (72-short stride), V staged TRANSPOSED [dim][key]
// (136-short stride) for key-contiguous B-frags; p^T aliased over K buffer.
// Continuous-path numerics only — bucket path untouched.
// BIT-EXACTNESS INVARIANTS (calibrated to host OpenBLAS, r1 PASS):
//  - qk GEMM: fp32 FMA chain ascending k, panel folds {384,704}, panel sums
//    combined by plain adds in panel order (RMW flush). DO NOT TOUCH.
//  - hash: ascending-f FMA chain, argmax first-occurrence strict >/<.

__device__ __forceinline__ bool qk_fold_point(int k0) {
    return k0 == 384 || k0 == 704;
}

typedef __attribute__((ext_vector_type(8))) short bf16x8;
typedef __attribute__((ext_vector_type(4))) short bf16x4s;
typedef __attribute__((ext_vector_type(4))) float f32x4;

#define MFMA_BF16(A, B, C) __builtin_amdgcn_mfma_f32_16x16x32_bf16(A, B, C, 0, 0, 0)

__device__ __forceinline__ unsigned short f2bf(float x) {
    unsigned u = __float_as_uint(x);
    u += 0x7FFFu + ((u >> 16) & 1u);
    return (unsigned short)(u >> 16);
}
__device__ __forceinline__ float bf2f(unsigned short hv) {
    return __uint_as_float(((unsigned)hv) << 16);
}

// ---- scratch in static device globals ----
__device__ static float g_qk32[32u * 4096u * 64u];   // 32 MB [m][t][d]
__device__ static float g_v32 [32u * 4096u * 64u];   // 32 MB
__device__ static float g_ctx [2u * 4096u * 1024u];  // 32 MB [b][t][head*64+d]
__device__ static float g_bo  [32u * 8u * 4096u * 64u]; // 256 MB [m][h][t][d]
__device__ static float g_logits[32u * 8u * 4096u];  //  4 MB [m][h][t]
__device__ static u16   g_st  [32u * 8u * 4096u];    //  2 MB sorted token idx
__device__ static u8    g_bkt [32u * 8u * 4096u];    //  1 MB bucket ids

// ---------------------------------------------------------------------------
// Kernel 1a: qkv GEMM. 128x128 C tile, 8x8 per thread, K-step 32, RMW
// fold-flush. grid (64, 16). (r8 version, replay-proven.)
// ---------------------------------------------------------------------------
__global__ __launch_bounds__(256) void qkv_gemm(
    const float* __restrict__ x, const float* __restrict__ w_qk,
    const float* __restrict__ w_v)
{
    __shared__ __align__(16) float As[32 * 132];  // [kk][row]
    __shared__ __align__(16) float Ws[32 * 192];  // [kk][(c>>3)*12 + (c&7)]
    const int tid = threadIdx.x;
    const int bm = blockIdx.x;
    const int bn = blockIdx.y;
    const bool is_v = bn >= 8;
    const float* __restrict__ w = is_v ? w_v : w_qk;
    const int hp = is_v ? bn - 8 : bn;
    const int ncol0 = hp * 128;
    const int row0 = bm * 128;
    const int tx = tid & 15, ty = tid >> 4;
    const int lr = tid >> 1;
    const int lk = (tid & 1) * 16;
    float acc[8][8] = {};

    const int b_ = row0 >> 12;
    const int head = hp * 2 + (tx >> 3);
    const int m = b_ * 16 + head;
    const int d0 = (tx * 8) & 63;
    float* __restrict__ dst = is_v ? g_v32 : g_qk32;
    int first_panel = 1;

    for (int k0 = 0; k0 < 1024; k0 += 32) {
        if (qk_fold_point(k0)) {
#pragma unroll
            for (int i = 0; i < 8; i++) {
                const int t = (row0 & 4095) + ty * 8 + i;
                float* __restrict__ cp =
                    &dst[(((size_t)m * 4096 + t) << 6) + d0];
                float4 s0, s1;
                s0.x = acc[i][0]; s0.y = acc[i][1];
                s0.z = acc[i][2]; s0.w = acc[i][3];
                s1.x = acc[i][4]; s1.y = acc[i][5];
                s1.z = acc[i][6]; s1.w = acc[i][7];
                if (!first_panel) {
                    const float4 c0 = *(const float4*)&cp[0];
                    const float4 c1 = *(const float4*)&cp[4];
                    s0.x += c0.x; s0.y += c0.y; s0.z += c0.z; s0.w += c0.w;
                    s1.x += c1.x; s1.y += c1.y; s1.z += c1.z; s1.w += c1.w;
                }
                *(float4*)&cp[0] = s0;
                *(float4*)&cp[4] = s1;
#pragma unroll
                for (int j = 0; j < 8; j++) acc[i][j] = 0.f;
            }
            first_panel = 0;
        }
        float av[16], wv[16];
#pragma unroll
        for (int q4 = 0; q4 < 4; q4++) {
            *(float4*)&av[q4 * 4] =
                *(const float4*)(x + (size_t)(row0 + lr) * 1024 + k0 + lk + q4 * 4);
            *(float4*)&wv[q4 * 4] =
                *(const float4*)(w + (size_t)(ncol0 + lr) * 1024 + k0 + lk + q4 * 4);
        }
        __syncthreads();
#pragma unroll
        for (int q = 0; q < 16; q++) {
            As[(lk + q) * 132 + lr] = av[q];
            Ws[(lk + q) * 192 + (lr >> 3) * 12 + (lr & 7)] = wv[q];
        }
        __syncthreads();
#pragma unroll 4
        for (int kk = 0; kk < 32; kk++) {
            const float4 a0 = *(const float4*)&As[kk * 132 + ty * 8];
            const float4 a1 = *(const float4*)&As[kk * 132 + ty * 8 + 4];
            const float4 b0 = *(const float4*)&Ws[kk * 192 + tx * 12];
            const float4 b1 = *(const float4*)&Ws[kk * 192 + tx * 12 + 4];
            const float aa[8] = {a0.x, a0.y, a0.z, a0.w, a1.x, a1.y, a1.z, a1.w};
            const float bb[8] = {b0.x, b0.y, b0.z, b0.w, b1.x, b1.y, b1.z, b1.w};
#pragma unroll
            for (int i = 0; i < 8; i++)
#pragma unroll
                for (int j = 0; j < 8; j++)
                    acc[i][j] = fmaf(aa[i], bb[j], acc[i][j]);
        }
    }
#pragma unroll
    for (int i = 0; i < 8; i++) {
        const int t = (row0 & 4095) + ty * 8 + i;
        float* __restrict__ cp = &dst[(((size_t)m * 4096 + t) << 6) + d0];
        const float4 c0 = *(const float4*)&cp[0];
        const float4 c1 = *(const float4*)&cp[4];
        float4 s0, s1;
        s0.x = acc[i][0] + c0.x; s0.y = acc[i][1] + c0.y;
        s0.z = acc[i][2] + c0.z; s0.w = acc[i][3] + c0.w;
        s1.x = acc[i][4] + c1.x; s1.y = acc[i][5] + c1.y;
        s1.z = acc[i][6] + c1.z; s1.w = acc[i][7] + c1.w;
        *(float4*)&cp[0] = s0;
        *(float4*)&cp[4] = s1;
    }
}

// ---------------------------------------------------------------------------
// Kernel 1b: LSH hash (unchanged, bit-pinned).
// ---------------------------------------------------------------------------
__global__ __launch_bounds__(256) void hash_kernel(
    const float* __restrict__ rot_in)
{
    __shared__ __align__(16) float rotS[16384];  // [f][h][i]
    const int tid = threadIdx.x;
    for (int idx = tid; idx < 16384; idx += 256)
        rotS[idx] = rot_in[idx];
    __syncthreads();
    const int row = blockIdx.x * 256 + tid;      // m*4096 + t
    const int m = row >> 12, t = row & 4095;
    float q[64];
    const float* __restrict__ qp = g_qk32 + ((size_t)row << 6);
#pragma unroll
    for (int f4 = 0; f4 < 16; f4++)
        *(float4*)&q[f4 * 4] = *(const float4*)&qp[f4 * 4];
#pragma unroll 1
    for (int hh = 0; hh < 8; hh++) {
        float bp = -3.4e38f; int ip = 0;
        float mn = 3.4e38f;  int im = 0;
#pragma unroll 1
        for (int ib = 0; ib < 8; ib++) {
            float s0 = 0.f, s1 = 0.f, s2 = 0.f, s3 = 0.f;
#pragma unroll
            for (int f = 0; f < 64; f++) {
                const float4 r4 =
                    *(const float4*)&rotS[f * 256 + hh * 32 + ib * 4];
                const float qf = q[f];
                s0 = fmaf(qf, r4.x, s0);
                s1 = fmaf(qf, r4.y, s1);
                s2 = fmaf(qf, r4.z, s2);
                s3 = fmaf(qf, r4.w, s3);
            }
            const int i0 = ib * 4;
            if (s0 > bp) { bp = s0; ip = i0; }
            if (s0 < mn) { mn = s0; im = i0; }
            if (s1 > bp) { bp = s1; ip = i0 + 1; }
            if (s1 < mn) { mn = s1; im = i0 + 1; }
            if (s2 > bp) { bp = s2; ip = i0 + 2; }
            if (s2 < mn) { mn = s2; im = i0 + 2; }
            if (s3 > bp) { bp = s3; ip = i0 + 3; }
            if (s3 < mn) { mn = s3; im = i0 + 3; }
        }
        const int bi = (-mn > bp) ? (32 + im) : ip;
        g_bkt[((size_t)m * 8 + hh) * 4096 + t] = (u8)bi;
    }
}

// ---------------------------------------------------------------------------
// Kernel 2: per-(m,h) stable counting sort (unchanged).
// ---------------------------------------------------------------------------
__global__ __launch_bounds__(256) void sort_kernel()
{
    __shared__ u16 hist[256 * 64];   // [chunk][bucket]
    __shared__ u8 bkt[4096];
    __shared__ int rowsum[64];
    __shared__ int rowbase[64];
    const int tid = threadIdx.x;
    const int mh = blockIdx.x;
    const u8* __restrict__ src = g_bkt + (size_t)mh * 4096;
    for (int i = tid; i < 4096; i += 256) bkt[i] = src[i];
    for (int i = tid; i < 16384; i += 256) hist[i] = 0;
    __syncthreads();
#pragma unroll
    for (int k = 0; k < 16; k++) {
        const int t = tid * 16 + k;
        hist[tid * 64 + (bkt[t] & 63)]++;  // own row -> race-free, stable
    }
    __syncthreads();
    if (tid < 64) {
        int s = 0;
        for (int c = 0; c < 256; c++) s += hist[c * 64 + tid];
        rowsum[tid] = s;
    }
    __syncthreads();
    if (tid == 0) {
        int acc = 0;
        for (int b = 0; b < 64; b++) { rowbase[b] = acc; acc += rowsum[b]; }
    }
    __syncthreads();
    if (tid < 64) {
        int run = rowbase[tid];
        for (int c = 0; c < 256; c++) {
            const int tmp = hist[c * 64 + tid];
            hist[c * 64 + tid] = (u16)run;
            run += tmp;
        }
    }
    __syncthreads();
    u16* __restrict__ dst = g_st + (size_t)mh * 4096;
#pragma unroll
    for (int k = 0; k < 16; k++) {
        const int t = tid * 16 + k;
        const int b = bkt[t] & 63;
        const int pos = hist[tid * 64 + b]++;
        dst[pos & 4095] = (u16)t;
    }
}

// ---------------------------------------------------------------------------
// Kernel 3: fused per-chunk attention, MFMA bf16-split.
// Block 256 = 4 waves; wave w owns q-row-tile [16w,16w+16).
// K in ksb/ksl [128 keys][72 shorts]; V transposed vth/vtl [64 dims][136];
// p^T (hi/lo) aliased over ksb/ksl after dots. LDS 72.7KB -> 2 blocks/CU.
// ---------------------------------------------------------------------------
__global__ __launch_bounds__(256) void attn_chunk()
{
    __shared__ __align__(16) short ksb[128 * 72];
    __shared__ __align__(16) short ksl[128 * 72];
    __shared__ __align__(16) short vth[64 * 136];
    __shared__ __align__(16) short vtl[64 * 136];
    __shared__ float rnorm[128];
    __shared__ int tk[128];
    const int tid = threadIdx.x;
    const int bid = blockIdx.x;
    const int m = bid >> 9, c = bid & 511;
    const int h = c >> 6, cc = c & 63;
    const int cp = (c + 511) & 511;            // look-one-back, wraps all 512
    const int hpp = cp >> 6, ccp = cp & 63;
    const u16* __restrict__ stm = g_st + (size_t)m * 8 * 4096;
    if (tid < 128) {
        const int hh = (tid < 64) ? h : hpp;
        const int cq = (tid < 64) ? cc : ccp;
        tk[tid] = (int)stm[hh * 4096 + cq * 64 + (tid & 63)] & 4095;
    }
    __syncthreads();
    const float* __restrict__ qkm = g_qk32 + ((size_t)m << 18);
    const float* __restrict__ vm = g_v32 + ((size_t)m << 18);
    // --- staging: K hi/lo [key][f]; V hi/lo transposed [f][key] ---
    for (int idx = tid; idx < 128 * 16; idx += 256) {
        const int j = idx >> 4, f4 = idx & 15;
        const size_t so = ((size_t)tk[j] << 6) + f4 * 4;
        const float4 kq = *(const float4*)&qkm[so];
        const float4 vv = *(const float4*)&vm[so];
        const float kq_[4] = {kq.x, kq.y, kq.z, kq.w};
        const float vv_[4] = {vv.x, vv.y, vv.z, vv.w};
        bf16x4s kh, kl;
#pragma unroll
        for (int e = 0; e < 4; e++) {
            const unsigned short hh_ = f2bf(kq_[e]);
            kh[e] = (short)hh_;
            kl[e] = (short)f2bf(kq_[e] - bf2f(hh_));
        }
        *(bf16x4s*)&ksb[j * 72 + f4 * 4] = kh;
        *(bf16x4s*)&ksl[j * 72 + f4 * 4] = kl;
#pragma unroll
        for (int e = 0; e < 4; e++) {
            const int f = f4 * 4 + e;
            const unsigned short vh_ = f2bf(vv_[e]);
            vth[f * 136 + j] = (short)vh_;
            vtl[f * 136 + j] = (short)f2bf(vv_[e] - bf2f(vh_));
        }
    }
    __syncthreads();
    if (tid < 128) {
        float ss = 0.f;
#pragma unroll
        for (int f8 = 0; f8 < 8; f8++) {
            const bf16x8 h8 = *(const bf16x8*)&ksb[tid * 72 + f8 * 8];
            const bf16x8 l8 = *(const bf16x8*)&ksl[tid * 72 + f8 * 8];
#pragma unroll
            for (int e = 0; e < 8; e++) {
                const float xv = bf2f((unsigned short)h8[e])
                               + bf2f((unsigned short)l8[e]);
                ss += xv * xv;
            }
        }
        rnorm[tid] = 1.0f / fmaxf(sqrtf(ss), 1e-12f);
    }
    __syncthreads();
    const int w = tid >> 6, lane = tid & 63;
    const int llo = lane & 15, lhi = lane >> 4;
    // --- dots: D[q 16 rows of wave][128 keys], K-split 2 x 32 ---
    bf16x8 Ah[2], Al[2];
#pragma unroll
    for (int ks2 = 0; ks2 < 2; ks2++) {
        const int off = (16 * w + llo) * 72 + ks2 * 32 + lhi * 8;
        Ah[ks2] = *(const bf16x8*)&ksb[off];
        Al[ks2] = *(const bf16x8*)&ksl[off];
    }
    f32x4 D[8];
#pragma unroll
    for (int ct = 0; ct < 8; ct++) D[ct] = f32x4{0.f, 0.f, 0.f, 0.f};
#pragma unroll
    for (int ct = 0; ct < 8; ct++) {
#pragma unroll
        for (int ks2 = 0; ks2 < 2; ks2++) {
            const int off = (16 * ct + llo) * 72 + ks2 * 32 + lhi * 8;
            const bf16x8 Bh = *(const bf16x8*)&ksb[off];
            const bf16x8 Bl = *(const bf16x8*)&ksl[off];
            D[ct] = MFMA_BF16(Ah[ks2], Bh, D[ct]);
            D[ct] = MFMA_BF16(Ah[ks2], Bl, D[ct]);
            D[ct] = MFMA_BF16(Al[ks2], Bh, D[ct]);
        }
    }
    // --- epilogue: mask/clamp + row softmax (16-lane reduce) ---
    int myq[4];
#pragma unroll
    for (int r = 0; r < 4; r++) myq[r] = tk[16 * w + lhi * 4 + r];
    float ev[8][4];
    float mx[4] = {-3.4e38f, -3.4e38f, -3.4e38f, -3.4e38f};
#pragma unroll
    for (int ct = 0; ct < 8; ct++) {
        const float rn_ = rnorm[16 * ct + llo] * 0.125f;
        const int tkey = tk[16 * ct + llo];
#pragma unroll
        for (int r = 0; r < 4; r++) {
            float a = D[ct][r];
            a = (myq[r] == tkey) ? -50000.f
                : fminf(fmaxf(a * rn_, -30.f), 30.f);
            ev[ct][r] = a;
            mx[r] = fmaxf(mx[r], a);
        }
    }
    float inv_s[4], lse_[4];
#pragma unroll
    for (int r = 0; r < 4; r++) {
        float mr = mx[r];
        mr = fmaxf(mr, __shfl_xor(mr, 1));
        mr = fmaxf(mr, __shfl_xor(mr, 2));
        mr = fmaxf(mr, __shfl_xor(mr, 4));
        mr = fmaxf(mr, __shfl_xor(mr, 8));
        float s = 0.f;
#pragma unroll
        for (int ct = 0; ct < 8; ct++) {
            const float e = __expf(ev[ct][r] - mr);
            ev[ct][r] = e;
            s += e;
        }
        s += __shfl_xor(s, 1);
        s += __shfl_xor(s, 2);
        s += __shfl_xor(s, 4);
        s += __shfl_xor(s, 8);
        inv_s[r] = 1.0f / s;
        lse_[r] = mr + __logf(s);
    }
    __syncthreads();   // all ksb/ksl dots reads done -> alias as p^T
    short* __restrict__ pth = ksb;   // [64 rows][136 keys]
    short* __restrict__ ptl = ksl;
#pragma unroll
    for (int ct = 0; ct < 8; ct++) {
        const int key = 16 * ct + llo;
#pragma unroll
        for (int r = 0; r < 4; r++) {
            const float ph = ev[ct][r] * inv_s[r];
            const unsigned short hh_ = f2bf(ph);
            const int q = 16 * w + lhi * 4 + r;
            pth[q * 136 + key] = (short)hh_;
            ptl[q * 136 + key] = (short)f2bf(ph - bf2f(hh_));
        }
    }
    if (llo == 0) {
#pragma unroll
        for (int r = 0; r < 4; r++)
            g_logits[((size_t)m * 8 + h) * 4096 + myq[r]] = lse_[r];
    }
    __syncthreads();
    // --- PV: O[q 16 rows][64 dims], K-split 4 x 32 keys ---
    bf16x8 Ph[4], Pl[4];
#pragma unroll
    for (int ks4 = 0; ks4 < 4; ks4++) {
        const int off = (16 * w + llo) * 136 + ks4 * 32 + lhi * 8;
        Ph[ks4] = *(const bf16x8*)&pth[off];
        Pl[ks4] = *(const bf16x8*)&ptl[off];
    }
    float* __restrict__ bo = g_bo + ((((size_t)m * 8 + h) * 4096) << 6);
#pragma unroll
    for (int ct2 = 0; ct2 < 4; ct2++) {
        f32x4 O = f32x4{0.f, 0.f, 0.f, 0.f};
#pragma unroll
        for (int ks4 = 0; ks4 < 4; ks4++) {
            const int off = (16 * ct2 + llo) * 136 + ks4 * 32 + lhi * 8;
            const bf16x8 Vh = *(const bf16x8*)&vth[off];
            const bf16x8 Vl = *(const bf16x8*)&vtl[off];
            O = MFMA_BF16(Ph[ks4], Vh, O);
            O = MFMA_BF16(Ph[ks4], Vl, O);
            O = MFMA_BF16(Pl[ks4], Vh, O);
        }
#pragma unroll
        for (int r = 0; r < 4; r++)
            bo[((size_t)myq[r] << 6) + 16 * ct2 + llo] = O[r];
    }
}

// ---------------------------------------------------------------------------
// Kernel 4: round combination (unchanged).
// ---------------------------------------------------------------------------
__global__ __launch_bounds__(256) void combine()
{
    const int idx = blockIdx.x * 256 + threadIdx.x;
    const int g = idx & 3;                 // 16-dim group
    const int t = (idx >> 2) & 4095;
    const int m = idx >> 14;
    const float* __restrict__ lg = g_logits + (size_t)m * 8 * 4096 + t;
    float l[8], mx = -3.4e38f;
#pragma unroll
    for (int h = 0; h < 8; h++) {
        l[h] = lg[(size_t)h * 4096];
        mx = fmaxf(mx, l[h]);
    }
    float s = 0.f;
#pragma unroll
    for (int h = 0; h < 8; h++) { l[h] = __expf(l[h] - mx); s += l[h]; }
    const float inv = 1.0f / s;
    const float* __restrict__ bo = g_bo
        + (((size_t)m * 8) * 4096 + t) * 64 + g * 16;
    float4 o0 = {0, 0, 0, 0}, o1 = {0, 0, 0, 0}, o2 = {0, 0, 0, 0}, o3 = {0, 0, 0, 0};
#pragma unroll
    for (int h = 0; h < 8; h++) {
        const float w = l[h] * inv;
        const size_t ho = (size_t)h * 4096 * 64;
        const float4 v0 = *(const float4*)&bo[ho + 0];
        const float4 v1 = *(const float4*)&bo[ho + 4];
        const float4 v2 = *(const float4*)&bo[ho + 8];
        const float4 v3 = *(const float4*)&bo[ho + 12];
        o0.x += w * v0.x; o0.y += w * v0.y; o0.z += w * v0.z; o0.w += w * v0.w;
        o1.x += w * v1.x; o1.y += w * v1.y; o1.z += w * v1.z; o1.w += w * v1.w;
        o2.x += w * v2.x; o2.y += w * v2.y; o2.z += w * v2.z; o2.w += w * v2.w;
        o3.x += w * v3.x; o3.y += w * v3.y; o3.z += w * v3.z; o3.w += w * v3.w;
    }
    float* __restrict__ cd = g_ctx
        + ((size_t)(m >> 4) * 4096 + t) * 1024 + (m & 15) * 64 + g * 16;
    *(float4*)&cd[0]  = o0;
    *(float4*)&cd[4]  = o1;
    *(float4*)&cd[8]  = o2;
    *(float4*)&cd[12] = o3;
}

// ---------------------------------------------------------------------------
// Kernel 5: out = ctx @ w_out^T + b_out. 128x128 tile (unchanged).
// ---------------------------------------------------------------------------
__global__ __launch_bounds__(256) void out_gemm(
    const float* __restrict__ w_out, const float* __restrict__ b_out,
    float* __restrict__ out)
{
    __shared__ __align__(16) float As[32 * 132];
    __shared__ __align__(16) float Ws[32 * 192];
    const int tid = threadIdx.x;
    const int bm = blockIdx.x, bn = blockIdx.y;
    const int row0 = bm * 128, col0 = bn * 128;
    const int tx = tid & 15, ty = tid >> 4;
    const int lr = tid >> 1;
    const int lk = (tid & 1) * 16;
    float acc[8][8] = {};

    for (int k0 = 0; k0 < 1024; k0 += 32) {
        float av[16], wv[16];
#pragma unroll
        for (int q4 = 0; q4 < 4; q4++) {
            *(float4*)&av[q4 * 4] =
                *(const float4*)(g_ctx + (size_t)(row0 + lr) * 1024 + k0 + lk + q4 * 4);
            *(float4*)&wv[q4 * 4] =
                *(const float4*)(w_out + (size_t)(col0 + lr) * 1024 + k0 + lk + q4 * 4);
        }
        __syncthreads();
#pragma unroll
        for (int q = 0; q < 16; q++) {
            As[(lk + q) * 132 + lr] = av[q];
            Ws[(lk + q) * 192 + (lr >> 3) * 12 + (lr & 7)] = wv[q];
        }
        __syncthreads();
#pragma unroll 4
        for (int kk = 0; kk < 32; kk++) {
            const float4 a0 = *(const float4*)&As[kk * 132 + ty * 8];
            const float4 a1 = *(const float4*)&As[kk * 132 + ty * 8 + 4];
            const float4 b0 = *(const float4*)&Ws[kk * 192 + tx * 12];
            const float4 b1 = *(const float4*)&Ws[kk * 192 + tx * 12 + 4];
            const float aa[8] = {a0.x, a0.y, a0.z, a0.w, a1.x, a1.y, a1.z, a1.w};
            const float bb[8] = {b0.x, b0.y, b0.z, b0.w, b1.x, b1.y, b1.z, b1.w};
#pragma unroll
            for (int i = 0; i < 8; i++)
#pragma unroll
                for (int j = 0; j < 8; j++)
                    acc[i][j] = fmaf(aa[i], bb[j], acc[i][j]);
        }
    }
#pragma unroll
    for (int i = 0; i < 8; i++) {
        const int row = row0 + ty * 8 + i;
        float4 s0, s1;
        s0.x = acc[i][0] + b_out[col0 + tx * 8 + 0];
        s0.y = acc[i][1] + b_out[col0 + tx * 8 + 1];
        s0.z = acc[i][2] + b_out[col0 + tx * 8 + 2];
        s0.w = acc[i][3] + b_out[col0 + tx * 8 + 3];
        s1.x = acc[i][4] + b_out[col0 + tx * 8 + 4];
        s1.y = acc[i][5] + b_out[col0 + tx * 8 + 5];
        s1.z = acc[i][6] + b_out[col0 + tx * 8 + 6];
        s1.w = acc[i][7] + b_out[col0 + tx * 8 + 7];
        *(float4*)&out[(size_t)row * 1024 + col0 + tx * 8] = s0;
        *(float4*)&out[(size_t)row * 1024 + col0 + tx * 8 + 4] = s1;
    }
}

// ---------------------------------------------------------------------------
extern "C" void kernel_launch(void* const* d_in, const int* in_sizes, int n_in,
                              void* d_out, int out_size, void* d_ws, size_t ws_size,
                              hipStream_t stream)
{
    (void)in_sizes; (void)n_in; (void)out_size; (void)d_ws; (void)ws_size;
    const float* x     = (const float*)d_in[0];
    const float* w_qk  = (const float*)d_in[1];
    const float* w_v   = (const float*)d_in[2];
    const float* w_out = (const float*)d_in[3];
    const float* b_out = (const float*)d_in[4];
    const float* rot   = (const float*)d_in[5];

    qkv_gemm<<<dim3(64, 16), 256, 0, stream>>>(x, w_qk, w_v);
    hash_kernel<<<512, 256, 0, stream>>>(rot);
    sort_kernel<<<256, 256, 0, stream>>>();
    attn_chunk<<<16384, 256, 0, stream>>>();
    combine<<<2048, 256, 0, stream>>>();
    out_gemm<<<dim3(64, 8), 256, 0, stream>>>(w_out, b_out, (float*)d_out);
}

// Round 12
// 1044.630 us; speedup vs baseline: 1.4873x; 1.2411x over previous
//
#include <hip/hip_runtime.h>
#include <hip/hip_bf16.h>

typedef unsigned short u16;
typedef unsigned char u8;

// Problem constants: B_=2, T=4096, DIM=1024, HEADS=16, DH=64, NH(rounds)=8,
// NB(buckets)=64, BUCKET=64, merged batch-heads M=32, chunks/merged-head=512.
//
// ROUND 22 (session r11): split qkv by NUMERICAL CONTRACT. Only the qk half
// feeds the hash argmax (bit-pinned); V and out_gemm are continuous-path,
// same status as attn_chunk (r10: MFMA'd with ZERO absmax movement).
//  - qk_gemm: r8 RMW fp32 kernel, grid (64,8) — bit-exact, DO NOT TOUCH.
//  - v_gemm:  NEW bf16 hi/lo 3-term MFMA GEMM (x @ w_v^T), err ~3e-6.
//  - out_gemm: same MFMA structure + bias.
// MFMA fragment layouts verbatim from r10-verified attn_chunk:
//   A[row=lane&15][k=(lane>>4)*8+e], B[col=lane&15][k=...], D[row=(lane>>4)*4+r][col=lane&15].
// LDS staging stride 40 shorts (80B): 16B-aligned b128, clean 2-way banks (free, m136).
// BIT-EXACTNESS INVARIANTS (calibrated to host OpenBLAS, r1 PASS):
//  - qk GEMM: fp32 FMA chain ascending k, panel folds {384,704}, panel sums
//    combined by plain adds in panel order (RMW flush).
//  - hash: ascending-f FMA chain, argmax first-occurrence strict >/<.

__device__ __forceinline__ bool qk_fold_point(int k0) {
    return k0 == 384 || k0 == 704;
}

typedef __attribute__((ext_vector_type(8))) short bf16x8;
typedef __attribute__((ext_vector_type(4))) short bf16x4s;
typedef __attribute__((ext_vector_type(4))) float f32x4;

#define MFMA_BF16(A, B, C) __builtin_amdgcn_mfma_f32_16x16x32_bf16(A, B, C, 0, 0, 0)

__device__ __forceinline__ unsigned short f2bf(float x) {
    unsigned u = __float_as_uint(x);
    u += 0x7FFFu + ((u >> 16) & 1u);
    return (unsigned short)(u >> 16);
}
__device__ __forceinline__ float bf2f(unsigned short hv) {
    return __uint_as_float(((unsigned)hv) << 16);
}

// ---- scratch in static device globals ----
__device__ static float g_qk32[32u * 4096u * 64u];   // 32 MB [m][t][d]
__device__ static float g_v32 [32u * 4096u * 64u];   // 32 MB
__device__ static float g_ctx [2u * 4096u * 1024u];  // 32 MB [b][t][head*64+d]
__device__ static float g_bo  [32u * 8u * 4096u * 64u]; // 256 MB [m][h][t][d]
__device__ static float g_logits[32u * 8u * 4096u];  //  4 MB [m][h][t]
__device__ static u16   g_st  [32u * 8u * 4096u];    //  2 MB sorted token idx
__device__ static u8    g_bkt [32u * 8u * 4096u];    //  1 MB bucket ids

// ---------------------------------------------------------------------------
// Kernel 1a: qk GEMM. 128x128 C tile, 8x8 per thread, K-step 32, RMW
// fold-flush. grid (64, 8). Bit-pinned fp32 chain (r8 version, replay-proven).
// ---------------------------------------------------------------------------
__global__ __launch_bounds__(256) void qk_gemm(
    const float* __restrict__ x, const float* __restrict__ w_qk)
{
    __shared__ __align__(16) float As[32 * 132];  // [kk][row]
    __shared__ __align__(16) float Ws[32 * 192];  // [kk][(c>>3)*12 + (c&7)]
    const int tid = threadIdx.x;
    const int bm = blockIdx.x;
    const int hp = blockIdx.y;          // head pair 0..7
    const int ncol0 = hp * 128;
    const int row0 = bm * 128;
    const int tx = tid & 15, ty = tid >> 4;
    const int lr = tid >> 1;
    const int lk = (tid & 1) * 16;
    float acc[8][8] = {};

    const int b_ = row0 >> 12;
    const int head = hp * 2 + (tx >> 3);
    const int m = b_ * 16 + head;
    const int d0 = (tx * 8) & 63;
    float* __restrict__ dst = g_qk32;
    int first_panel = 1;

    for (int k0 = 0; k0 < 1024; k0 += 32) {
        if (qk_fold_point(k0)) {
#pragma unroll
            for (int i = 0; i < 8; i++) {
                const int t = (row0 & 4095) + ty * 8 + i;
                float* __restrict__ cp =
                    &dst[(((size_t)m * 4096 + t) << 6) + d0];
                float4 s0, s1;
                s0.x = acc[i][0]; s0.y = acc[i][1];
                s0.z = acc[i][2]; s0.w = acc[i][3];
                s1.x = acc[i][4]; s1.y = acc[i][5];
                s1.z = acc[i][6]; s1.w = acc[i][7];
                if (!first_panel) {
                    const float4 c0 = *(const float4*)&cp[0];
                    const float4 c1 = *(const float4*)&cp[4];
                    s0.x += c0.x; s0.y += c0.y; s0.z += c0.z; s0.w += c0.w;
                    s1.x += c1.x; s1.y += c1.y; s1.z += c1.z; s1.w += c1.w;
                }
                *(float4*)&cp[0] = s0;
                *(float4*)&cp[4] = s1;
#pragma unroll
                for (int j = 0; j < 8; j++) acc[i][j] = 0.f;
            }
            first_panel = 0;
        }
        float av[16], wv[16];
#pragma unroll
        for (int q4 = 0; q4 < 4; q4++) {
            *(float4*)&av[q4 * 4] =
                *(const float4*)(x + (size_t)(row0 + lr) * 1024 + k0 + lk + q4 * 4);
            *(float4*)&wv[q4 * 4] =
                *(const float4*)(w_qk + (size_t)(ncol0 + lr) * 1024 + k0 + lk + q4 * 4);
        }
        __syncthreads();
#pragma unroll
        for (int q = 0; q < 16; q++) {
            As[(lk + q) * 132 + lr] = av[q];
            Ws[(lk + q) * 192 + (lr >> 3) * 12 + (lr & 7)] = wv[q];
        }
        __syncthreads();
#pragma unroll 4
        for (int kk = 0; kk < 32; kk++) {
            const float4 a0 = *(const float4*)&As[kk * 132 + ty * 8];
            const float4 a1 = *(const float4*)&As[kk * 132 + ty * 8 + 4];
            const float4 b0 = *(const float4*)&Ws[kk * 192 + tx * 12];
            const float4 b1 = *(const float4*)&Ws[kk * 192 + tx * 12 + 4];
            const float aa[8] = {a0.x, a0.y, a0.z, a0.w, a1.x, a1.y, a1.z, a1.w};
            const float bb[8] = {b0.x, b0.y, b0.z, b0.w, b1.x, b1.y, b1.z, b1.w};
#pragma unroll
            for (int i = 0; i < 8; i++)
#pragma unroll
                for (int j = 0; j < 8; j++)
                    acc[i][j] = fmaf(aa[i], bb[j], acc[i][j]);
        }
    }
#pragma unroll
    for (int i = 0; i < 8; i++) {
        const int t = (row0 & 4095) + ty * 8 + i;
        float* __restrict__ cp = &dst[(((size_t)m * 4096 + t) << 6) + d0];
        const float4 c0 = *(const float4*)&cp[0];
        const float4 c1 = *(const float4*)&cp[4];
        float4 s0, s1;
        s0.x = acc[i][0] + c0.x; s0.y = acc[i][1] + c0.y;
        s0.z = acc[i][2] + c0.z; s0.w = acc[i][3] + c0.w;
        s1.x = acc[i][4] + c1.x; s1.y = acc[i][5] + c1.y;
        s1.z = acc[i][6] + c1.z; s1.w = acc[i][7] + c1.w;
        *(float4*)&cp[0] = s0;
        *(float4*)&cp[4] = s1;
    }
}

// ---------------------------------------------------------------------------
// Kernel 1a': V GEMM via bf16 hi/lo 3-term MFMA (continuous path).
// 128x128 tile, 4 waves, wave = 64x64 (4x4 16-tiles). grid (64, 8).
// LDS: A/B hi/lo, 128 rows x 40 shorts (16B-aligned, 2-way banks = free).
// ---------------------------------------------------------------------------
__global__ __launch_bounds__(256) void v_gemm(
    const float* __restrict__ x, const float* __restrict__ w_v)
{
    __shared__ __align__(16) short Ah[128 * 40], Al[128 * 40];
    __shared__ __align__(16) short Bh[128 * 40], Bl[128 * 40];
    const int tid = threadIdx.x;
    const int row0 = blockIdx.x * 128;
    const int col0 = blockIdx.y * 128;
    const int w = tid >> 6, lane = tid & 63;
    const int llo = lane & 15, lhi = lane >> 4;
    const int wr0 = (w >> 1) * 64, wc0 = (w & 1) * 64;
    const int lr = tid >> 1;            // stage row 0..127
    const int lh = (tid & 1) * 16;      // stage k-offset {0,16}
    f32x4 Acc[4][4];
#pragma unroll
    for (int rt = 0; rt < 4; rt++)
#pragma unroll
        for (int ct = 0; ct < 4; ct++) Acc[rt][ct] = f32x4{0.f, 0.f, 0.f, 0.f};

    for (int k0 = 0; k0 < 1024; k0 += 32) {
        float av[16], bv[16];
#pragma unroll
        for (int q4 = 0; q4 < 4; q4++) {
            *(float4*)&av[q4 * 4] =
                *(const float4*)(x + (size_t)(row0 + lr) * 1024 + k0 + lh + q4 * 4);
            *(float4*)&bv[q4 * 4] =
                *(const float4*)(w_v + (size_t)(col0 + lr) * 1024 + k0 + lh + q4 * 4);
        }
        __syncthreads();
        short ah[16], al2[16], bh2[16], bl2[16];
#pragma unroll
        for (int e = 0; e < 16; e++) {
            unsigned short hv = f2bf(av[e]);
            ah[e] = (short)hv;
            al2[e] = (short)f2bf(av[e] - bf2f(hv));
            hv = f2bf(bv[e]);
            bh2[e] = (short)hv;
            bl2[e] = (short)f2bf(bv[e] - bf2f(hv));
        }
        *(bf16x8*)&Ah[lr * 40 + lh] = *(bf16x8*)&ah[0];
        *(bf16x8*)&Ah[lr * 40 + lh + 8] = *(bf16x8*)&ah[8];
        *(bf16x8*)&Al[lr * 40 + lh] = *(bf16x8*)&al2[0];
        *(bf16x8*)&Al[lr * 40 + lh + 8] = *(bf16x8*)&al2[8];
        *(bf16x8*)&Bh[lr * 40 + lh] = *(bf16x8*)&bh2[0];
        *(bf16x8*)&Bh[lr * 40 + lh + 8] = *(bf16x8*)&bh2[8];
        *(bf16x8*)&Bl[lr * 40 + lh] = *(bf16x8*)&bl2[0];
        *(bf16x8*)&Bl[lr * 40 + lh + 8] = *(bf16x8*)&bl2[8];
        __syncthreads();
        bf16x8 Afh[4], Afl[4];
#pragma unroll
        for (int rt = 0; rt < 4; rt++) {
            const int off = (wr0 + rt * 16 + llo) * 40 + lhi * 8;
            Afh[rt] = *(const bf16x8*)&Ah[off];
            Afl[rt] = *(const bf16x8*)&Al[off];
        }
#pragma unroll
        for (int ct = 0; ct < 4; ct++) {
            const int off = (wc0 + ct * 16 + llo) * 40 + lhi * 8;
            const bf16x8 Bfh = *(const bf16x8*)&Bh[off];
            const bf16x8 Bfl = *(const bf16x8*)&Bl[off];
#pragma unroll
            for (int rt = 0; rt < 4; rt++) {
                Acc[rt][ct] = MFMA_BF16(Afh[rt], Bfh, Acc[rt][ct]);
                Acc[rt][ct] = MFMA_BF16(Afh[rt], Bfl, Acc[rt][ct]);
                Acc[rt][ct] = MFMA_BF16(Afl[rt], Bfh, Acc[rt][ct]);
            }
        }
    }
    // epilogue: scatter into g_v32 [m][t][d]
#pragma unroll
    for (int rt = 0; rt < 4; rt++) {
#pragma unroll
        for (int ct = 0; ct < 4; ct++) {
            const int col = col0 + wc0 + ct * 16 + llo;
            const int hd = col >> 6, d = col & 63;
#pragma unroll
            for (int r = 0; r < 4; r++) {
                const int row = row0 + wr0 + rt * 16 + lhi * 4 + r;
                const int m = ((row >> 12) << 4) + hd;
                const int t = row & 4095;
                g_v32[(((size_t)m * 4096 + t) << 6) + d] = Acc[rt][ct][r];
            }
        }
    }
}

// ---------------------------------------------------------------------------
// Kernel 1b: LSH hash (unchanged, bit-pinned).
// ---------------------------------------------------------------------------
__global__ __launch_bounds__(256) void hash_kernel(
    const float* __restrict__ rot_in)
{
    __shared__ __align__(16) float rotS[16384];  // [f][h][i]
    const int tid = threadIdx.x;
    for (int idx = tid; idx < 16384; idx += 256)
        rotS[idx] = rot_in[idx];
    __syncthreads();
    const int row = blockIdx.x * 256 + tid;      // m*4096 + t
    const int m = row >> 12, t = row & 4095;
    float q[64];
    const float* __restrict__ qp = g_qk32 + ((size_t)row << 6);
#pragma unroll
    for (int f4 = 0; f4 < 16; f4++)
        *(float4*)&q[f4 * 4] = *(const float4*)&qp[f4 * 4];
#pragma unroll 1
    for (int hh = 0; hh < 8; hh++) {
        float bp = -3.4e38f; int ip = 0;
        float mn = 3.4e38f;  int im = 0;
#pragma unroll 1
        for (int ib = 0; ib < 8; ib++) {
            float s0 = 0.f, s1 = 0.f, s2 = 0.f, s3 = 0.f;
#pragma unroll
            for (int f = 0; f < 64; f++) {
                const float4 r4 =
                    *(const float4*)&rotS[f * 256 + hh * 32 + ib * 4];
                const float qf = q[f];
                s0 = fmaf(qf, r4.x, s0);
                s1 = fmaf(qf, r4.y, s1);
                s2 = fmaf(qf, r4.z, s2);
                s3 = fmaf(qf, r4.w, s3);
            }
            const int i0 = ib * 4;
            if (s0 > bp) { bp = s0; ip = i0; }
            if (s0 < mn) { mn = s0; im = i0; }
            if (s1 > bp) { bp = s1; ip = i0 + 1; }
            if (s1 < mn) { mn = s1; im = i0 + 1; }
            if (s2 > bp) { bp = s2; ip = i0 + 2; }
            if (s2 < mn) { mn = s2; im = i0 + 2; }
            if (s3 > bp) { bp = s3; ip = i0 + 3; }
            if (s3 < mn) { mn = s3; im = i0 + 3; }
        }
        const int bi = (-mn > bp) ? (32 + im) : ip;
        g_bkt[((size_t)m * 8 + hh) * 4096 + t] = (u8)bi;
    }
}

// ---------------------------------------------------------------------------
// Kernel 2: per-(m,h) stable counting sort (unchanged).
// ---------------------------------------------------------------------------
__global__ __launch_bounds__(256) void sort_kernel()
{
    __shared__ u16 hist[256 * 64];   // [chunk][bucket]
    __shared__ u8 bkt[4096];
    __shared__ int rowsum[64];
    __shared__ int rowbase[64];
    const int tid = threadIdx.x;
    const int mh = blockIdx.x;
    const u8* __restrict__ src = g_bkt + (size_t)mh * 4096;
    for (int i = tid; i < 4096; i += 256) bkt[i] = src[i];
    for (int i = tid; i < 16384; i += 256) hist[i] = 0;
    __syncthreads();
#pragma unroll
    for (int k = 0; k < 16; k++) {
        const int t = tid * 16 + k;
        hist[tid * 64 + (bkt[t] & 63)]++;  // own row -> race-free, stable
    }
    __syncthreads();
    if (tid < 64) {
        int s = 0;
        for (int c = 0; c < 256; c++) s += hist[c * 64 + tid];
        rowsum[tid] = s;
    }
    __syncthreads();
    if (tid == 0) {
        int acc = 0;
        for (int b = 0; b < 64; b++) { rowbase[b] = acc; acc += rowsum[b]; }
    }
    __syncthreads();
    if (tid < 64) {
        int run = rowbase[tid];
        for (int c = 0; c < 256; c++) {
            const int tmp = hist[c * 64 + tid];
            hist[c * 64 + tid] = (u16)run;
            run += tmp;
        }
    }
    __syncthreads();
    u16* __restrict__ dst = g_st + (size_t)mh * 4096;
#pragma unroll
    for (int k = 0; k < 16; k++) {
        const int t = tid * 16 + k;
        const int b = bkt[t] & 63;
        const int pos = hist[tid * 64 + b]++;
        dst[pos & 4095] = (u16)t;
    }
}

// ---------------------------------------------------------------------------
// Kernel 3: fused per-chunk attention, MFMA bf16-split (r10, verified).
// ---------------------------------------------------------------------------
__global__ __launch_bounds__(256) void attn_chunk()
{
    __shared__ __align__(16) short ksb[128 * 72];
    __shared__ __align__(16) short ksl[128 * 72];
    __shared__ __align__(16) short vth[64 * 136];
    __shared__ __align__(16) short vtl[64 * 136];
    __shared__ float rnorm[128];
    __shared__ int tk[128];
    const int tid = threadIdx.x;
    const int bid = blockIdx.x;
    const int m = bid >> 9, c = bid & 511;
    const int h = c >> 6, cc = c & 63;
    const int cp = (c + 511) & 511;            // look-one-back, wraps all 512
    const int hpp = cp >> 6, ccp = cp & 63;
    const u16* __restrict__ stm = g_st + (size_t)m * 8 * 4096;
    if (tid < 128) {
        const int hh = (tid < 64) ? h : hpp;
        const int cq = (tid < 64) ? cc : ccp;
        tk[tid] = (int)stm[hh * 4096 + cq * 64 + (tid & 63)] & 4095;
    }
    __syncthreads();
    const float* __restrict__ qkm = g_qk32 + ((size_t)m << 18);
    const float* __restrict__ vm = g_v32 + ((size_t)m << 18);
    // --- staging: K hi/lo [key][f]; V hi/lo transposed [f][key] ---
    for (int idx = tid; idx < 128 * 16; idx += 256) {
        const int j = idx >> 4, f4 = idx & 15;
        const size_t so = ((size_t)tk[j] << 6) + f4 * 4;
        const float4 kq = *(const float4*)&qkm[so];
        const float4 vv = *(const float4*)&vm[so];
        const float kq_[4] = {kq.x, kq.y, kq.z, kq.w};
        const float vv_[4] = {vv.x, vv.y, vv.z, vv.w};
        bf16x4s kh, kl;
#pragma unroll
        for (int e = 0; e < 4; e++) {
            const unsigned short hh_ = f2bf(kq_[e]);
            kh[e] = (short)hh_;
            kl[e] = (short)f2bf(kq_[e] - bf2f(hh_));
        }
        *(bf16x4s*)&ksb[j * 72 + f4 * 4] = kh;
        *(bf16x4s*)&ksl[j * 72 + f4 * 4] = kl;
#pragma unroll
        for (int e = 0; e < 4; e++) {
            const int f = f4 * 4 + e;
            const unsigned short vh_ = f2bf(vv_[e]);
            vth[f * 136 + j] = (short)vh_;
            vtl[f * 136 + j] = (short)f2bf(vv_[e] - bf2f(vh_));
        }
    }
    __syncthreads();
    if (tid < 128) {
        float ss = 0.f;
#pragma unroll
        for (int f8 = 0; f8 < 8; f8++) {
            const bf16x8 h8 = *(const bf16x8*)&ksb[tid * 72 + f8 * 8];
            const bf16x8 l8 = *(const bf16x8*)&ksl[tid * 72 + f8 * 8];
#pragma unroll
            for (int e = 0; e < 8; e++) {
                const float xv = bf2f((unsigned short)h8[e])
                               + bf2f((unsigned short)l8[e]);
                ss += xv * xv;
            }
        }
        rnorm[tid] = 1.0f / fmaxf(sqrtf(ss), 1e-12f);
    }
    __syncthreads();
    const int w = tid >> 6, lane = tid & 63;
    const int llo = lane & 15, lhi = lane >> 4;
    // --- dots: D[q 16 rows of wave][128 keys], K-split 2 x 32 ---
    bf16x8 Ah[2], Al[2];
#pragma unroll
    for (int ks2 = 0; ks2 < 2; ks2++) {
        const int off = (16 * w + llo) * 72 + ks2 * 32 + lhi * 8;
        Ah[ks2] = *(const bf16x8*)&ksb[off];
        Al[ks2] = *(const bf16x8*)&ksl[off];
    }
    f32x4 D[8];
#pragma unroll
    for (int ct = 0; ct < 8; ct++) D[ct] = f32x4{0.f, 0.f, 0.f, 0.f};
#pragma unroll
    for (int ct = 0; ct < 8; ct++) {
#pragma unroll
        for (int ks2 = 0; ks2 < 2; ks2++) {
            const int off = (16 * ct + llo) * 72 + ks2 * 32 + lhi * 8;
            const bf16x8 Bh = *(const bf16x8*)&ksb[off];
            const bf16x8 Bl = *(const bf16x8*)&ksl[off];
            D[ct] = MFMA_BF16(Ah[ks2], Bh, D[ct]);
            D[ct] = MFMA_BF16(Ah[ks2], Bl, D[ct]);
            D[ct] = MFMA_BF16(Al[ks2], Bh, D[ct]);
        }
    }
    // --- epilogue: mask/clamp + row softmax (16-lane reduce) ---
    int myq[4];
#pragma unroll
    for (int r = 0; r < 4; r++) myq[r] = tk[16 * w + lhi * 4 + r];
    float ev[8][4];
    float mx[4] = {-3.4e38f, -3.4e38f, -3.4e38f, -3.4e38f};
#pragma unroll
    for (int ct = 0; ct < 8; ct++) {
        const float rn_ = rnorm[16 * ct + llo] * 0.125f;
        const int tkey = tk[16 * ct + llo];
#pragma unroll
        for (int r = 0; r < 4; r++) {
            float a = D[ct][r];
            a = (myq[r] == tkey) ? -50000.f
                : fminf(fmaxf(a * rn_, -30.f), 30.f);
            ev[ct][r] = a;
            mx[r] = fmaxf(mx[r], a);
        }
    }
    float inv_s[4], lse_[4];
#pragma unroll
    for (int r = 0; r < 4; r++) {
        float mr = mx[r];
        mr = fmaxf(mr, __shfl_xor(mr, 1));
        mr = fmaxf(mr, __shfl_xor(mr, 2));
        mr = fmaxf(mr, __shfl_xor(mr, 4));
        mr = fmaxf(mr, __shfl_xor(mr, 8));
        float s = 0.f;
#pragma unroll
        for (int ct = 0; ct < 8; ct++) {
            const float e = __expf(ev[ct][r] - mr);
            ev[ct][r] = e;
            s += e;
        }
        s += __shfl_xor(s, 1);
        s += __shfl_xor(s, 2);
        s += __shfl_xor(s, 4);
        s += __shfl_xor(s, 8);
        inv_s[r] = 1.0f / s;
        lse_[r] = mr + __logf(s);
    }
    __syncthreads();   // all ksb/ksl dots reads done -> alias as p^T
    short* __restrict__ pth = ksb;   // [64 rows][136 keys]
    short* __restrict__ ptl = ksl;
#pragma unroll
    for (int ct = 0; ct < 8; ct++) {
        const int key = 16 * ct + llo;
#pragma unroll
        for (int r = 0; r < 4; r++) {
            const float ph = ev[ct][r] * inv_s[r];
            const unsigned short hh_ = f2bf(ph);
            const int q = 16 * w + lhi * 4 + r;
            pth[q * 136 + key] = (short)hh_;
            ptl[q * 136 + key] = (short)f2bf(ph - bf2f(hh_));
        }
    }
    if (llo == 0) {
#pragma unroll
        for (int r = 0; r < 4; r++)
            g_logits[((size_t)m * 8 + h) * 4096 + myq[r]] = lse_[r];
    }
    __syncthreads();
    // --- PV: O[q 16 rows][64 dims], K-split 4 x 32 keys ---
    bf16x8 Ph[4], Pl[4];
#pragma unroll
    for (int ks4 = 0; ks4 < 4; ks4++) {
        const int off = (16 * w + llo) * 136 + ks4 * 32 + lhi * 8;
        Ph[ks4] = *(const bf16x8*)&pth[off];
        Pl[ks4] = *(const bf16x8*)&ptl[off];
    }
    float* __restrict__ bo = g_bo + ((((size_t)m * 8 + h) * 4096) << 6);
#pragma unroll
    for (int ct2 = 0; ct2 < 4; ct2++) {
        f32x4 O = f32x4{0.f, 0.f, 0.f, 0.f};
#pragma unroll
        for (int ks4 = 0; ks4 < 4; ks4++) {
            const int off = (16 * ct2 + llo) * 136 + ks4 * 32 + lhi * 8;
            const bf16x8 Vh = *(const bf16x8*)&vth[off];
            const bf16x8 Vl = *(const bf16x8*)&vtl[off];
            O = MFMA_BF16(Ph[ks4], Vh, O);
            O = MFMA_BF16(Ph[ks4], Vl, O);
            O = MFMA_BF16(Pl[ks4], Vh, O);
        }
#pragma unroll
        for (int r = 0; r < 4; r++)
            bo[((size_t)myq[r] << 6) + 16 * ct2 + llo] = O[r];
    }
}

// ---------------------------------------------------------------------------
// Kernel 4: round combination (unchanged).
// ---------------------------------------------------------------------------
__global__ __launch_bounds__(256) void combine()
{
    const int idx = blockIdx.x * 256 + threadIdx.x;
    const int g = idx & 3;                 // 16-dim group
    const int t = (idx >> 2) & 4095;
    const int m = idx >> 14;
    const float* __restrict__ lg = g_logits + (size_t)m * 8 * 4096 + t;
    float l[8], mx = -3.4e38f;
#pragma unroll
    for (int h = 0; h < 8; h++) {
        l[h] = lg[(size_t)h * 4096];
        mx = fmaxf(mx, l[h]);
    }
    float s = 0.f;
#pragma unroll
    for (int h = 0; h < 8; h++) { l[h] = __expf(l[h] - mx); s += l[h]; }
    const float inv = 1.0f / s;
    const float* __restrict__ bo = g_bo
        + (((size_t)m * 8) * 4096 + t) * 64 + g * 16;
    float4 o0 = {0, 0, 0, 0}, o1 = {0, 0, 0, 0}, o2 = {0, 0, 0, 0}, o3 = {0, 0, 0, 0};
#pragma unroll
    for (int h = 0; h < 8; h++) {
        const float w = l[h] * inv;
        const size_t ho = (size_t)h * 4096 * 64;
        const float4 v0 = *(const float4*)&bo[ho + 0];
        const float4 v1 = *(const float4*)&bo[ho + 4];
        const float4 v2 = *(const float4*)&bo[ho + 8];
        const float4 v3 = *(const float4*)&bo[ho + 12];
        o0.x += w * v0.x; o0.y += w * v0.y; o0.z += w * v0.z; o0.w += w * v0.w;
        o1.x += w * v1.x; o1.y += w * v1.y; o1.z += w * v1.z; o1.w += w * v1.w;
        o2.x += w * v2.x; o2.y += w * v2.y; o2.z += w * v2.z; o2.w += w * v2.w;
        o3.x += w * v3.x; o3.y += w * v3.y; o3.z += w * v3.z; o3.w += w * v3.w;
    }
    float* __restrict__ cd = g_ctx
        + ((size_t)(m >> 4) * 4096 + t) * 1024 + (m & 15) * 64 + g * 16;
    *(float4*)&cd[0]  = o0;
    *(float4*)&cd[4]  = o1;
    *(float4*)&cd[8]  = o2;
    *(float4*)&cd[12] = o3;
}

// ---------------------------------------------------------------------------
// Kernel 5: out = ctx @ w_out^T + b_out via bf16 hi/lo 3-term MFMA.
// Same structure as v_gemm. grid (64, 8).
// ---------------------------------------------------------------------------
__global__ __launch_bounds__(256) void out_gemm(
    const float* __restrict__ w_out, const float* __restrict__ b_out,
    float* __restrict__ out)
{
    __shared__ __align__(16) short Ah[128 * 40], Al[128 * 40];
    __shared__ __align__(16) short Bh[128 * 40], Bl[128 * 40];
    const int tid = threadIdx.x;
    const int row0 = blockIdx.x * 128;
    const int col0 = blockIdx.y * 128;
    const int w = tid >> 6, lane = tid & 63;
    const int llo = lane & 15, lhi = lane >> 4;
    const int wr0 = (w >> 1) * 64, wc0 = (w & 1) * 64;
    const int lr = tid >> 1;
    const int lh = (tid & 1) * 16;
    f32x4 Acc[4][4];
#pragma unroll
    for (int rt = 0; rt < 4; rt++)
#pragma unroll
        for (int ct = 0; ct < 4; ct++) Acc[rt][ct] = f32x4{0.f, 0.f, 0.f, 0.f};

    for (int k0 = 0; k0 < 1024; k0 += 32) {
        float av[16], bv[16];
#pragma unroll
        for (int q4 = 0; q4 < 4; q4++) {
            *(float4*)&av[q4 * 4] =
                *(const float4*)(g_ctx + (size_t)(row0 + lr) * 1024 + k0 + lh + q4 * 4);
            *(float4*)&bv[q4 * 4] =
                *(const float4*)(w_out + (size_t)(col0 + lr) * 1024 + k0 + lh + q4 * 4);
        }
        __syncthreads();
        short ah[16], al2[16], bh2[16], bl2[16];
#pragma unroll
        for (int e = 0; e < 16; e++) {
            unsigned short hv = f2bf(av[e]);
            ah[e] = (short)hv;
            al2[e] = (short)f2bf(av[e] - bf2f(hv));
            hv = f2bf(bv[e]);
            bh2[e] = (short)hv;
            bl2[e] = (short)f2bf(bv[e] - bf2f(hv));
        }
        *(bf16x8*)&Ah[lr * 40 + lh] = *(bf16x8*)&ah[0];
        *(bf16x8*)&Ah[lr * 40 + lh + 8] = *(bf16x8*)&ah[8];
        *(bf16x8*)&Al[lr * 40 + lh] = *(bf16x8*)&al2[0];
        *(bf16x8*)&Al[lr * 40 + lh + 8] = *(bf16x8*)&al2[8];
        *(bf16x8*)&Bh[lr * 40 + lh] = *(bf16x8*)&bh2[0];
        *(bf16x8*)&Bh[lr * 40 + lh + 8] = *(bf16x8*)&bh2[8];
        *(bf16x8*)&Bl[lr * 40 + lh] = *(bf16x8*)&bl2[0];
        *(bf16x8*)&Bl[lr * 40 + lh + 8] = *(bf16x8*)&bl2[8];
        __syncthreads();
        bf16x8 Afh[4], Afl[4];
#pragma unroll
        for (int rt = 0; rt < 4; rt++) {
            const int off = (wr0 + rt * 16 + llo) * 40 + lhi * 8;
            Afh[rt] = *(const bf16x8*)&Ah[off];
            Afl[rt] = *(const bf16x8*)&Al[off];
        }
#pragma unroll
        for (int ct = 0; ct < 4; ct++) {
            const int off = (wc0 + ct * 16 + llo) * 40 + lhi * 8;
            const bf16x8 Bfh = *(const bf16x8*)&Bh[off];
            const bf16x8 Bfl = *(const bf16x8*)&Bl[off];
#pragma unroll
            for (int rt = 0; rt < 4; rt++) {
                Acc[rt][ct] = MFMA_BF16(Afh[rt], Bfh, Acc[rt][ct]);
                Acc[rt][ct] = MFMA_BF16(Afh[rt], Bfl, Acc[rt][ct]);
                Acc[rt][ct] = MFMA_BF16(Afl[rt], Bfh, Acc[rt][ct]);
            }
        }
    }
#pragma unroll
    for (int ct = 0; ct < 4; ct++) {
        const int col = col0 + wc0 + ct * 16 + llo;
        const float bias = b_out[col];
#pragma unroll
        for (int rt = 0; rt < 4; rt++) {
#pragma unroll
            for (int r = 0; r < 4; r++) {
                const int row = row0 + wr0 + rt * 16 + lhi * 4 + r;
                out[(size_t)row * 1024 + col] = Acc[rt][ct][r] + bias;
            }
        }
    }
}

// ---------------------------------------------------------------------------
extern "C" void kernel_launch(void* const* d_in, const int* in_sizes, int n_in,
                              void* d_out, int out_size, void* d_ws, size_t ws_size,
                              hipStream_t stream)
{
    (void)in_sizes; (void)n_in; (void)out_size; (void)d_ws; (void)ws_size;
    const float* x     = (const float*)d_in[0];
    const float* w_qk  = (const float*)d_in[1];
    const float* w_v   = (const float*)d_in[2];
    const float* w_out = (const float*)d_in[3];
    const float* b_out = (const float*)d_in[4];
    const float* rot   = (const float*)d_in[5];

    qk_gemm<<<dim3(64, 8), 256, 0, stream>>>(x, w_qk);
    v_gemm<<<dim3(64, 8), 256, 0, stream>>>(x, w_v);
    hash_kernel<<<512, 256, 0, stream>>>(rot);
    sort_kernel<<<256, 256, 0, stream>>>();
    attn_chunk<<<16384, 256, 0, stream>>>();
    combine<<<2048, 256, 0, stream>>>();
    out_gemm<<<dim3(64, 8), 256, 0, stream>>>(w_out, b_out, (float*)d_out);
}